// Round 7
// baseline (503.157 us; speedup 1.0000x reference)
//
#include <hip/hip_runtime.h>

// BLOOM attention block on MI355X (gfx950).
// GEMMs: proven 128x128 global_load_lds structure (round-2/5, ~838 TF) with
// XCD-bijective block chunking (T1). 8-phase 256^2 abandoned after three
// regressions (r3/r4/r6: 270-300us vs 246us) — no cross-wave overlap at
// 1 blk/CU reproduces the template's gain in this harness.
// Attention: flash w/ alibi+causal, longest-first dispatch + XCD head-chunk,
// exp2-domain softmax + defer-max rescale (T13).

#define SEQL 2048
#define HIDN 4096
#define NHEAD 32
#define HDIM 128
#define H3 12288

typedef __bf16 bf16x8 __attribute__((ext_vector_type(8)));
typedef float f32x4 __attribute__((ext_vector_type(4)));
typedef unsigned short u16x8 __attribute__((ext_vector_type(8)));

__device__ __forceinline__ unsigned short f2bf(float f) {
  union { float f; unsigned u; } v; v.f = f;
  return (unsigned short)((v.u + 0x7FFFu + ((v.u >> 16) & 1u)) >> 16);
}

__device__ __forceinline__ void gload_lds16(const void* g, void* l) {
  __builtin_amdgcn_global_load_lds(
      (const __attribute__((address_space(1))) void*)g,
      (__attribute__((address_space(3))) void*)l, 16, 0, 0);
}

__global__ __launch_bounds__(256) void cvt_f32_bf16(
    const float* __restrict__ in, unsigned short* __restrict__ out, long long n) {
  long long i = ((long long)blockIdx.x * blockDim.x + threadIdx.x) * 8;
  long long stride = (long long)gridDim.x * blockDim.x * 8;
  for (; i < n; i += stride) {
    float4 a = *(const float4*)(in + i);
    float4 b = *(const float4*)(in + i + 4);
    u16x8 o;
    o[0] = f2bf(a.x); o[1] = f2bf(a.y); o[2] = f2bf(a.z); o[3] = f2bf(a.w);
    o[4] = f2bf(b.x); o[5] = f2bf(b.y); o[6] = f2bf(b.z); o[7] = f2bf(b.w);
    *(u16x8*)(out + i) = o;
  }
}

// C[M,N] = A[M,K] * B[N,K]^T (+ epilogue). A,B bf16 (ushort bits).
// 128x128 tile, BK=64, 4 waves (2x2 of 64x64), 16x16x32 MFMA, 4x4 frags/wave.
// LDS[r][j16] = G[r][j16^(r&7)] via linear-dest global_load_lds with
// pre-swizzled source chunk (row&7 == lane>>3); reads XOR byte^((r&7)<<4).
// 1-D grid, XCD-bijective chunking: XCD c = b&7 gets contiguous lin chunk.
// EPI==0: QKV scatter epilogue (bias + write q/k/v_t as bf16).
// EPI==1: out = acc + bias[col] + residual[row*N+col], fp32.
template <int EPI>
__global__ __launch_bounds__(256) void gemm_nt(
    const unsigned short* __restrict__ A, const unsigned short* __restrict__ B,
    int M, int N, int K,
    const float* __restrict__ bias, const float* __restrict__ residual,
    float* __restrict__ outf,
    unsigned short* __restrict__ q_bf, unsigned short* __restrict__ k_bf,
    unsigned short* __restrict__ v_t) {
  __shared__ unsigned short As[128 * 64];  // 16 KiB
  __shared__ unsigned short Bs[128 * 64];  // 16 KiB

  const int tid = threadIdx.x;
  const int l = tid & 63;
  const int w = tid >> 6;
  const int wr = (w >> 1) * 64;   // wave row offset in tile
  const int wc = (w & 1) * 64;    // wave col offset in tile

  // XCD-bijective remap (nb = gridDim.x, multiple of 8; M/128 = 16).
  const int nb = gridDim.x;
  const int lin = (blockIdx.x & 7) * (nb >> 3) + (blockIdx.x >> 3);
  const int tm0 = (lin & 15) * 128;
  const int tn0 = (lin >> 4) * 128;

  const int lr = l >> 3;          // staging row-in-chunk
  const int lc = (l & 7) ^ lr;    // pre-swizzled 16B source chunk

  f32x4 acc[4][4] = {};

  for (int kt = 0; kt < K; kt += 64) {
    __syncthreads();
#pragma unroll
    for (int i = 0; i < 4; ++i) {
      const int row = w * 32 + i * 8 + lr;
      gload_lds16(&A[(long long)(tm0 + row) * K + kt + lc * 8],
                  (char*)As + (w * 4 + i) * 1024);
      gload_lds16(&B[(long long)(tn0 + row) * K + kt + lc * 8],
                  (char*)Bs + (w * 4 + i) * 1024);
    }
    __syncthreads();
#pragma unroll
    for (int kk = 0; kk < 2; ++kk) {
      const int colb = kk * 64 + (l >> 4) * 16;  // byte offset in row
      bf16x8 af[4], bfr[4];
#pragma unroll
      for (int m = 0; m < 4; ++m) {
        int row = wr + m * 16 + (l & 15);
        af[m] = *(const bf16x8*)((char*)As + row * 128 + (colb ^ ((row & 7) << 4)));
      }
#pragma unroll
      for (int n = 0; n < 4; ++n) {
        int row = wc + n * 16 + (l & 15);
        bfr[n] = *(const bf16x8*)((char*)Bs + row * 128 + (colb ^ ((row & 7) << 4)));
      }
#pragma unroll
      for (int m = 0; m < 4; ++m)
#pragma unroll
        for (int n = 0; n < 4; ++n)
          acc[m][n] = __builtin_amdgcn_mfma_f32_16x16x32_bf16(af[m], bfr[n], acc[m][n], 0, 0, 0);
    }
  }

  // Epilogue. D layout: col = lane&15, row = (lane>>4)*4 + reg (m89-verified).
#pragma unroll
  for (int m = 0; m < 4; ++m) {
#pragma unroll
    for (int n = 0; n < 4; ++n) {
      const int col = tn0 + wc + n * 16 + (l & 15);
      const float bv = bias[col];
#pragma unroll
      for (int r = 0; r < 4; ++r) {
        const int rowg = tm0 + wr + m * 16 + (l >> 4) * 4 + r;
        float v = acc[m][n][r] + bv;
        if (EPI == 0) {
          // fused[s, head*384 + which*128 + d]
          const int head = col / 384;
          const int rem = col - head * 384;
          const int which = rem >> 7;
          const int d = rem & 127;
          const unsigned short bv16 = f2bf(v);
          if (which == 0)
            q_bf[(long long)(head * SEQL + rowg) * HDIM + d] = bv16;
          else if (which == 1)
            k_bf[(long long)(head * SEQL + rowg) * HDIM + d] = bv16;
          else
            v_t[(long long)(head * HDIM + d) * SEQL + rowg] = bv16;
        } else {
          const long long idx = (long long)rowg * N + col;
          outf[idx] = v + residual[idx];
        }
      }
    }
  }
}

// Flash attention with alibi + causal mask. exp2-domain softmax + defer-max.
// 1-D grid of 1024 blocks. XCD c = b&7 owns heads [4c,4c+4);
// q-tiles dispatched longest-first within each XCD for tail packing.
// Block: one head x 64 q rows. 4 waves, each owns 16 q rows. KV tiles of 64.
__global__ __launch_bounds__(256) void attn_fwd(
    const unsigned short* __restrict__ q_bf, const unsigned short* __restrict__ k_bf,
    const unsigned short* __restrict__ v_t, const float* __restrict__ alibi,
    unsigned short* __restrict__ ctx_bf) {
  __shared__ unsigned short Ks[64 * 128];   // 16 KiB (rows = kv, 256B/row)
  __shared__ unsigned short Vs[128 * 64];   // 16 KiB (rows = d, 128B/row)
  __shared__ unsigned short Ps[4][16 * 64]; // 8 KiB  (per-wave P tile)
  __shared__ float Al[SEQL];                // 8 KiB  (alibi*log2e for this head)

  const int tid = threadIdx.x;
  const int l = tid & 63;
  const int w = tid >> 6;

  const float LOG2E = 1.4426950408889634f;

  // remap: b -> (head, qtile). xcd = b&7; i = b>>3 in [0,128);
  // head = xcd*4 + (i&3); qtile = 31 - (i>>2)  (longest first).
  const int b = blockIdx.x;
  const int i_ = b >> 3;
  const int h = (b & 7) * 4 + (i_ & 3);
  const int qtile = 31 - (i_ >> 2);
  const int qw = qtile * 64 + w * 16;  // this wave's q-row base

  for (int i = tid; i < SEQL; i += 256) Al[i] = alibi[h * SEQL + i] * LOG2E;

  // Q fragments: lane l holds row qw+(l&15), cols kk*32+(l>>4)*8..+7
  bf16x8 qf[4];
  {
    const unsigned short* qp =
        &q_bf[(long long)(h * SEQL + qw + (l & 15)) * HDIM + (l >> 4) * 8];
#pragma unroll
    for (int kk = 0; kk < 4; ++kk) qf[kk] = *(const bf16x8*)(qp + kk * 32);
  }

  f32x4 oacc[8] = {};
  float mrun[4] = {-__builtin_inff(), -__builtin_inff(), -__builtin_inff(), -__builtin_inff()};
  float lrun[4] = {0.f, 0.f, 0.f, 0.f};
  // inv_norm * log2(e): scores go straight to the exp2 domain.
  const float inv_norm2 = 0.08838834764831845f * 1.4426950408889634f;

  const int kR = l >> 4, kC = l & 15;
  const int vR = l >> 3, vC = (l & 7) ^ vR;

  const int ntiles = qtile + 1;  // causal
  for (int t = 0; t < ntiles; ++t) {
    const int kv0 = t * 64;
    __syncthreads();
#pragma unroll
    for (int i = 0; i < 4; ++i) {
      const int krow = w * 16 + i * 4 + kR;
      const int ksrc = kC ^ ((i & 1) * 4 + kR);
      gload_lds16(&k_bf[(long long)(h * SEQL + kv0 + krow) * HDIM + ksrc * 8],
                  (char*)Ks + (w * 4 + i) * 1024);
      const int vrow = w * 32 + i * 8 + vR;
      gload_lds16(&v_t[(long long)(h * HDIM + vrow) * SEQL + kv0 + vC * 8],
                  (char*)Vs + (w * 4 + i) * 1024);
    }
    __syncthreads();

    f32x4 sacc[4] = {};
#pragma unroll
    for (int kk = 0; kk < 4; ++kk) {
      const int colb = kk * 64 + (l >> 4) * 16;
#pragma unroll
      for (int n = 0; n < 4; ++n) {
        int row = n * 16 + (l & 15);
        bf16x8 kf = *(const bf16x8*)((char*)Ks + row * 256 + (colb ^ ((row & 7) << 4)));
        sacc[n] = __builtin_amdgcn_mfma_f32_16x16x32_bf16(qf[kk], kf, sacc[n], 0, 0, 0);
      }
    }

    // alibi + scale (exp2 domain) + causal mask
    float sc[4][4];  // [n][r]
#pragma unroll
    for (int n = 0; n < 4; ++n) {
      const int kv = kv0 + n * 16 + (l & 15);
      const float al = Al[kv];
#pragma unroll
      for (int r = 0; r < 4; ++r) {
        const int qrow = qw + (l >> 4) * 4 + r;
        float v = al + inv_norm2 * sacc[n][r];
        sc[n][r] = (kv > qrow) ? -__builtin_inff() : v;
      }
    }

    // online softmax per q row (16 lanes hold one row's scores, 4 cols each).
    // Defer-max (T13): only rescale when the tile max exceeds the running
    // max by >11 (exp2 headroom 2048, safe in bf16 P / f32 accum).
#pragma unroll
    for (int r = 0; r < 4; ++r) {
      float m0 = fmaxf(fmaxf(sc[0][r], sc[1][r]), fmaxf(sc[2][r], sc[3][r]));
      m0 = fmaxf(m0, __shfl_xor(m0, 1, 64));
      m0 = fmaxf(m0, __shfl_xor(m0, 2, 64));
      m0 = fmaxf(m0, __shfl_xor(m0, 4, 64));
      m0 = fmaxf(m0, __shfl_xor(m0, 8, 64));
      if (__ballot(m0 > mrun[r] + 11.0f)) {
        const float mnew = fmaxf(mrun[r], m0);
        const float scale = exp2f(mrun[r] - mnew);  // 0 on first tile
        mrun[r] = mnew;
        lrun[r] *= scale;
#pragma unroll
        for (int n2 = 0; n2 < 8; ++n2) oacc[n2][r] *= scale;
      }
      float p0 = 0.f;
#pragma unroll
      for (int n = 0; n < 4; ++n) {
        const float pv = exp2f(sc[n][r] - mrun[r]);  // -inf -> 0
        sc[n][r] = pv;
        p0 += pv;
      }
      p0 += __shfl_xor(p0, 1, 64);
      p0 += __shfl_xor(p0, 2, 64);
      p0 += __shfl_xor(p0, 4, 64);
      p0 += __shfl_xor(p0, 8, 64);
      lrun[r] += p0;
    }

    // P -> per-wave LDS (bf16, swizzled), then re-read as MFMA A fragments
#pragma unroll
    for (int n = 0; n < 4; ++n)
#pragma unroll
      for (int r = 0; r < 4; ++r) {
        const int row = (l >> 4) * 4 + r;
        const int colp = n * 16 + (l & 15);
        *(unsigned short*)((char*)Ps[w] + row * 128 + ((colp * 2) ^ ((row & 7) << 4))) =
            f2bf(sc[n][r]);
      }
    __threadfence_block();  // order per-wave LDS write->read
    bf16x8 pf[2];
#pragma unroll
    for (int kk2 = 0; kk2 < 2; ++kk2) {
      const int row = l & 15;
      const int colb = kk2 * 64 + (l >> 4) * 16;
      pf[kk2] = *(const bf16x8*)((char*)Ps[w] + row * 128 + (colb ^ ((row & 7) << 4)));
    }

    // PV: ctx[16][128] += P[16][64] @ V[64][128]
#pragma unroll
    for (int n2 = 0; n2 < 8; ++n2) {
#pragma unroll
      for (int kk2 = 0; kk2 < 2; ++kk2) {
        const int row = n2 * 16 + (l & 15);  // d row in Vs
        const int colb = kk2 * 64 + (l >> 4) * 16;
        bf16x8 vf = *(const bf16x8*)((char*)Vs + row * 128 + (colb ^ ((row & 7) << 4)));
        oacc[n2] = __builtin_amdgcn_mfma_f32_16x16x32_bf16(pf[kk2], vf, oacc[n2], 0, 0, 0);
      }
    }
  }

  // write ctx as bf16 [s][H], col = h*128 + d
#pragma unroll
  for (int n2 = 0; n2 < 8; ++n2)
#pragma unroll
    for (int r = 0; r < 4; ++r) {
      const int qrow = qw + (l >> 4) * 4 + r;
      const int col = h * HDIM + n2 * 16 + (l & 15);
      ctx_bf[(long long)qrow * HIDN + col] = f2bf(oacc[n2][r] / lrun[r]);
    }
}

extern "C" void kernel_launch(void* const* d_in, const int* in_sizes, int n_in,
                              void* d_out, int out_size, void* d_ws, size_t ws_size,
                              hipStream_t stream) {
  const float* hidden = (const float*)d_in[0];
  const float* residual = (const float*)d_in[1];
  const float* alibi = (const float*)d_in[2];
  // d_in[3]: attention_mask (bool) — causal mask computed analytically
  const float* Wqkv = (const float*)d_in[4];
  const float* bqkv = (const float*)d_in[5];
  const float* Wd = (const float*)d_in[6];
  const float* bd = (const float*)d_in[7];
  float* out = (float*)d_out;

  char* ws = (char*)d_ws;
  const size_t MB16 = 16777216;
  unsigned short* q_bf = (unsigned short*)(ws);
  unsigned short* k_bf = (unsigned short*)(ws + MB16);
  unsigned short* v_t = (unsigned short*)(ws + 2 * MB16);
  unsigned short* hid_bf = (unsigned short*)(ws + 3 * MB16);
  unsigned short* wqkv_bf = (unsigned short*)(ws + 4 * MB16);  // 96 MiB
  unsigned short* wd_bf = (unsigned short*)(ws + 4 * MB16);    // reuse after QKV GEMM
  unsigned short* ctx_bf = (unsigned short*)(ws + 4 * MB16 + 33554432);

  // 1. convert inputs to bf16
  cvt_f32_bf16<<<4096, 256, 0, stream>>>(hidden, hid_bf, (long long)SEQL * HIDN);
  cvt_f32_bf16<<<24576, 256, 0, stream>>>(Wqkv, wqkv_bf, (long long)H3 * HIDN);

  // 2. QKV projection (128^2, XCD-chunked) with interleaved-scatter epilogue
  gemm_nt<0><<<(SEQL / 128) * (H3 / 128), 256, 0, stream>>>(
      hid_bf, wqkv_bf, SEQL, H3, HIDN, bqkv, nullptr, nullptr, q_bf, k_bf, v_t);

  // 3. convert Wd (reuses Wqkv region — stream-ordered after QKV GEMM)
  cvt_f32_bf16<<<8192, 256, 0, stream>>>(Wd, wd_bf, (long long)HIDN * HIDN);

  // 4. flash attention (alibi + causal), longest-first + XCD head-chunking
  attn_fwd<<<NHEAD * (SEQL / 64), 256, 0, stream>>>(q_bf, k_bf, v_t, alibi, ctx_bf);

  // 5. output projection + bias + residual (fp32 out)
  gemm_nt<1><<<(SEQL / 128) * (HIDN / 128), 256, 0, stream>>>(
      ctx_bf, wd_bf, SEQL, HIDN, HIDN, bd, residual, out, nullptr, nullptr, nullptr);
}